// Round 13
// baseline (104919.421 us; speedup 1.0000x reference)
//
#include <hip/hip_runtime.h>

#define T_LEN 131072
#define HDIM  100
#define KPAD  112            // 100 h | 5 x | 1 bias-one | 6 zero
#define NROWS 400
#define NTHR  256
#define LOG2E 1.4426950408889634f

typedef __attribute__((ext_vector_type(2))) float f32x2;

// R13: back to the ONLY configuration that ever held ~200 weight floats in
// registers: 256 threads / 4 waves / __launch_bounds__(256,1) / plain
// contiguous float4 row loads (R3: VGPR=224). All 448/512-thread variants
// pinned/attributed/LDS-capped landed at VGPR 84-102 (R6-R12).
// Structure: quad q<50 owns hidden units {q, q+50}; lane g owns augmented
// cols [28g,28g+28). 8 gate-rows x 28 cols = 224 weights/thread. One h-slice
// feeds all 8 rows -> only 28 ds_read_b128/CU/step (vs 49 at 448thr).
// Loop: 7 rolling h-blocks, 112 pk_fma, 2-step quad DPP butterfly on 8
// partials, both cell updates lane-local (replicated x4), lane0 writes 2 h's,
// ONE barrier (double-buffered LDS). Prep kernel (verified R9-R12) builds
// pre-scaled augmented Waug[400][112] in d_ws.

template <int PAT>
__device__ __forceinline__ float qdpp(float v) {
    return __int_as_float(__builtin_amdgcn_mov_dpp(__float_as_int(v), PAT, 0xf, 0xf, true));
}

__global__ __launch_bounds__(256, 1)
void lstm_prep_kernel(const float* __restrict__ W_ih,
                      const float* __restrict__ W_hh,
                      const float* __restrict__ b_ih,
                      const float* __restrict__ b_hh,
                      float* __restrict__ ws)
{
    const int idx = blockIdx.x * 256 + threadIdx.x;
    if (idx >= NROWS * KPAD) return;
    const int row = idx / KPAD;
    const int col = idx - row * KPAD;
    const float sc = ((row >= 2 * HDIM) && (row < 3 * HDIM)) ? 2.f * LOG2E : LOG2E;
    float wv;
    if      (col < HDIM)      wv = W_hh[row * HDIM + col];
    else if (col < HDIM + 5)  wv = W_ih[row * 5 + (col - HDIM)];
    else if (col == HDIM + 5) wv = b_ih[row] + b_hh[row];
    else                      wv = 0.f;
    ws[idx] = wv * sc;
}

__global__ __launch_bounds__(NTHR, 1)
void lstm_seq_kernel(const float* __restrict__ input_seq,
                     const float* __restrict__ ws,
                     const float* __restrict__ W_lin,
                     const float* __restrict__ b_lin,
                     float* __restrict__ out)
{
    __shared__ __align__(16) float hbuf[2][KPAD];

    const int tid = threadIdx.x;
    const int q   = tid >> 2;            // quad id 0..63
    const int g   = tid & 3;             // K-slice id
    const bool act = q < 50;
    const int jA  = act ? q : 0;         // first hidden unit
    const int jB  = jA + 50;             // second hidden unit
    const int cb  = 28 * g;              // first col of this lane's slice

    // ---- 8 row pointers, 56 float4 weights: plain contiguous loads ----
    const float4* __restrict__ wp0 = (const float4*)(ws + (0 * HDIM + jA) * KPAD + cb);
    const float4* __restrict__ wp1 = (const float4*)(ws + (1 * HDIM + jA) * KPAD + cb);
    const float4* __restrict__ wp2 = (const float4*)(ws + (2 * HDIM + jA) * KPAD + cb);
    const float4* __restrict__ wp3 = (const float4*)(ws + (3 * HDIM + jA) * KPAD + cb);
    const float4* __restrict__ wp4 = (const float4*)(ws + (0 * HDIM + jB) * KPAD + cb);
    const float4* __restrict__ wp5 = (const float4*)(ws + (1 * HDIM + jB) * KPAD + cb);
    const float4* __restrict__ wp6 = (const float4*)(ws + (2 * HDIM + jB) * KPAD + cb);
    const float4* __restrict__ wp7 = (const float4*)(ws + (3 * HDIM + jB) * KPAD + cb);
#define WROW(r) \
    const float4 w##r##_0 = wp##r[0]; const float4 w##r##_1 = wp##r[1]; \
    const float4 w##r##_2 = wp##r[2]; const float4 w##r##_3 = wp##r[3]; \
    const float4 w##r##_4 = wp##r[4]; const float4 w##r##_5 = wp##r[5]; \
    const float4 w##r##_6 = wp##r[6];
    WROW(0) WROW(1) WROW(2) WROW(3) WROW(4) WROW(5) WROW(6) WROW(7)
#undef WROW

    // ---- init LDS: h=0 both buffers, x_0 in buf0, bias-one in both ----
    if (tid < 2 * KPAD) ((float*)hbuf)[tid] = 0.f;
    __syncthreads();
    if (tid < 5) hbuf[0][HDIM + tid] = input_seq[tid];
    if (tid == 5) { hbuf[0][HDIM + 5] = 1.f; hbuf[1][HDIM + 5] = 1.f; }
    __syncthreads();

    float cA = 0.f, cB = 0.f;            // cell states, replicated in the quad

    for (int t = 0; t < T_LEN; ++t) {
        // prefetch next x (5 lanes), latency hidden under the matvec
        float xn = 0.f;
        if (tid < 5) {
            const int tn = (t + 1 < T_LEN) ? (t + 1) : (T_LEN - 1);
            xn = input_seq[tn * 5 + tid];
        }

        const float4* __restrict__ hp = (const float4*)(hbuf[t & 1] + cb);

        // 8 gate-row partials (1 f32x2 acc each), rolling 2-deep h-blocks
        f32x2 p0 = f32x2{0.f, 0.f}, p1 = f32x2{0.f, 0.f};
        f32x2 p2 = f32x2{0.f, 0.f}, p3 = f32x2{0.f, 0.f};
        f32x2 p4 = f32x2{0.f, 0.f}, p5 = f32x2{0.f, 0.f};
        f32x2 p6 = f32x2{0.f, 0.f}, p7 = f32x2{0.f, 0.f};
#define FMB(HQ, K) {                                            \
        const f32x2 hA = f32x2{HQ.x, HQ.y};                     \
        const f32x2 hB = f32x2{HQ.z, HQ.w};                     \
        p0 = hA * f32x2{w0_##K.x, w0_##K.y} + p0;               \
        p0 = hB * f32x2{w0_##K.z, w0_##K.w} + p0;               \
        p1 = hA * f32x2{w1_##K.x, w1_##K.y} + p1;               \
        p1 = hB * f32x2{w1_##K.z, w1_##K.w} + p1;               \
        p2 = hA * f32x2{w2_##K.x, w2_##K.y} + p2;               \
        p2 = hB * f32x2{w2_##K.z, w2_##K.w} + p2;               \
        p3 = hA * f32x2{w3_##K.x, w3_##K.y} + p3;               \
        p3 = hB * f32x2{w3_##K.z, w3_##K.w} + p3;               \
        p4 = hA * f32x2{w4_##K.x, w4_##K.y} + p4;               \
        p4 = hB * f32x2{w4_##K.z, w4_##K.w} + p4;               \
        p5 = hA * f32x2{w5_##K.x, w5_##K.y} + p5;               \
        p5 = hB * f32x2{w5_##K.z, w5_##K.w} + p5;               \
        p6 = hA * f32x2{w6_##K.x, w6_##K.y} + p6;               \
        p6 = hB * f32x2{w6_##K.z, w6_##K.w} + p6;               \
        p7 = hA * f32x2{w7_##K.x, w7_##K.y} + p7;               \
        p7 = hB * f32x2{w7_##K.z, w7_##K.w} + p7; }
        {
            float4 hq0 = hp[0];
            float4 hq1 = hp[1];
            FMB(hq0, 0)
            float4 hq2 = hp[2];
            FMB(hq1, 1)
            float4 hq3 = hp[3];
            FMB(hq2, 2)
            float4 hq4 = hp[4];
            FMB(hq3, 3)
            float4 hq5 = hp[5];
            FMB(hq4, 4)
            float4 hq6 = hp[6];
            FMB(hq5, 5)
            FMB(hq6, 6)
        }
#undef FMB
        float z0 = p0.x + p0.y, z1 = p1.x + p1.y;
        float z2 = p2.x + p2.y, z3 = p3.x + p3.y;
        float z4 = p4.x + p4.y, z5 = p5.x + p5.y;
        float z6 = p6.x + p6.y, z7 = p7.x + p7.y;

        // quad butterfly: after xor1+xor2 every lane holds full z's
        z0 += qdpp<0xB1>(z0); z1 += qdpp<0xB1>(z1);
        z2 += qdpp<0xB1>(z2); z3 += qdpp<0xB1>(z3);
        z4 += qdpp<0xB1>(z4); z5 += qdpp<0xB1>(z5);
        z6 += qdpp<0xB1>(z6); z7 += qdpp<0xB1>(z7);
        z0 += qdpp<0x4E>(z0); z1 += qdpp<0x4E>(z1);
        z2 += qdpp<0x4E>(z2); z3 += qdpp<0x4E>(z3);
        z4 += qdpp<0x4E>(z4); z5 += qdpp<0x4E>(z5);
        z6 += qdpp<0x4E>(z6); z7 += qdpp<0x4E>(z7);

        // gates (rows pre-scaled: sigmoid by log2e, tanh by 2log2e)
        const float siA = __builtin_amdgcn_rcpf(1.f + __builtin_amdgcn_exp2f(-z0));
        const float sfA = __builtin_amdgcn_rcpf(1.f + __builtin_amdgcn_exp2f(-z1));
        const float ggA = fmaf(2.f, __builtin_amdgcn_rcpf(1.f + __builtin_amdgcn_exp2f(-z2)), -1.f);
        const float soA = __builtin_amdgcn_rcpf(1.f + __builtin_amdgcn_exp2f(-z3));
        const float siB = __builtin_amdgcn_rcpf(1.f + __builtin_amdgcn_exp2f(-z4));
        const float sfB = __builtin_amdgcn_rcpf(1.f + __builtin_amdgcn_exp2f(-z5));
        const float ggB = fmaf(2.f, __builtin_amdgcn_rcpf(1.f + __builtin_amdgcn_exp2f(-z6)), -1.f);
        const float soB = __builtin_amdgcn_rcpf(1.f + __builtin_amdgcn_exp2f(-z7));

        // cell updates (replicated across the quad's 4 lanes)
        cA = fmaf(sfA, cA, siA * ggA);
        cB = fmaf(sfB, cB, siB * ggB);
        const float thA = fmaf(2.f, __builtin_amdgcn_rcpf(1.f + __builtin_amdgcn_exp2f(cA * (-2.f * LOG2E))), -1.f);
        const float thB = fmaf(2.f, __builtin_amdgcn_rcpf(1.f + __builtin_amdgcn_exp2f(cB * (-2.f * LOG2E))), -1.f);
        const float hvA = soA * thA;
        const float hvB = soB * thB;

        float* __restrict__ hn = hbuf[(t + 1) & 1];
        if ((g == 0) & act) { hn[jA] = hvA; hn[jB] = hvB; }
        if (tid < 5) hn[HDIM + tid] = xn;
        __syncthreads();                 // single barrier per step

    }

    // epilogue: out = b_lin + W_lin . h_T   (T_LEN even -> h_T in hbuf[0])
    if (tid == 0) {
        float acc = b_lin[0];
        #pragma unroll
        for (int k = 0; k < HDIM; ++k) acc += W_lin[k] * hbuf[0][k];
        out[0] = acc;
    }
}

extern "C" void kernel_launch(void* const* d_in, const int* in_sizes, int n_in,
                              void* d_out, int out_size, void* d_ws, size_t ws_size,
                              hipStream_t stream) {
    const float* input_seq = (const float*)d_in[0];
    const float* W_ih      = (const float*)d_in[1];
    const float* W_hh      = (const float*)d_in[2];
    const float* b_ih      = (const float*)d_in[3];
    const float* b_hh      = (const float*)d_in[4];
    const float* W_lin     = (const float*)d_in[5];
    const float* b_lin     = (const float*)d_in[6];
    float* out = (float*)d_out;
    float* ws  = (float*)d_ws;           // needs 400*112*4 = 179,200 B

    const int nprep = NROWS * KPAD;
    lstm_prep_kernel<<<(nprep + 255) / 256, 256, 0, stream>>>(W_ih, W_hh, b_ih, b_hh, ws);
    lstm_seq_kernel<<<1, NTHR, 0, stream>>>(input_seq, ws, W_lin, b_lin, out);
}